// Round 9
// baseline (125.379 us; speedup 1.0000x reference)
//
#include <hip/hip_runtime.h>

#define NG 512
#define NF 32
#define NP (96 * 96 * 16)   // 147456 points
#define TPB 512             // 8 waves; 64 points per block, 8 gaussian segments
#define PTS 64
#define NSEG 8
#define CPS 2               // chunks (of 32 gaussians) per segment
#define RSTR 20             // LDS row stride in dwords (80 B), bank-spread (R12)

typedef _Float16 half8 __attribute__((ext_vector_type(8)));
typedef __fp16  fp16x2 __attribute__((ext_vector_type(2)));
typedef float f32x4 __attribute__((ext_vector_type(4)));
typedef unsigned uint4v __attribute__((ext_vector_type(4)));
typedef unsigned uint2v __attribute__((ext_vector_type(2)));

union H2U { fp16x2 h; unsigned u; };
union FRAG { unsigned u[4]; uint4v v; half8 h; };

#if defined(__has_builtin)
#if __has_builtin(__builtin_amdgcn_permlane16_swap) && __has_builtin(__builtin_amdgcn_permlane32_swap)
#define HAVE_PERMLANE_SWAP 1
#endif
#endif

__device__ __forceinline__ unsigned packh(__fp16 a, __fp16 b) {
    H2U p; p.h = (fp16x2){a, b}; return p.u;
}
__device__ __forceinline__ unsigned pkrtz(float a, float b) {
    H2U p; p.h = __builtin_amdgcn_cvt_pkrtz(a, b); return p.u;
}
// LDS image [512 rows][20 dw]; used ONLY for the phi prologue and the
// compose epilogue (chunks are LDS-free since R15). Dword 16 = tT.
__device__ __forceinline__ int ridx(int row, int grp) {
    return row * RSTR + 4 * grp;
}

// R16: cross-quad combine on the VALU pipe (per-SIMD) instead of DS pipe
// (per-CU, shared by all 24 resident waves — the top contended resource by
// cycle count). permlane16_swap(P,P) -> (rows[p0,p0,p2,p2], [p1,p1,p3,p3]);
// permlane32_swap(s,s) -> ([s_lo x4],[s_hi x4]). Products are operand-
// identical to the R15 shfl version -> bit-identical numerics.
__device__ __forceinline__ void quad_scan(float P, int quad,
                                          float& x, float& t, float& Pall)
{
#ifdef HAVE_PERMLANE_SWAP
    auto r = __builtin_amdgcn_permlane16_swap(
        __float_as_uint(P), __float_as_uint(P), false, false);
    float ea = __uint_as_float(r[0]);   // [p0,p0,p2,p2] per 16-row
    float eb = __uint_as_float(r[1]);   // [p1,p1,p3,p3]
    x = (quad & 1) ? ea : eb;           // other row in the 32-pair
    float s = ea * eb;                  // pair product, replicated
    auto r2 = __builtin_amdgcn_permlane32_swap(
        __float_as_uint(s), __float_as_uint(s), false, false);
    float fa = __uint_as_float(r2[0]);  // [s_lo x4]
    float fb = __uint_as_float(r2[1]);  // [s_hi x4]
    t = (quad & 2) ? fa : fb;           // other pair's product
    Pall = fa * fb;
#else
    x = __shfl_xor(P, 16);
    float s = P * x;
    t = __shfl_xor(s, 32);
    Pall = s * t;
#endif
}

// ---------------------------------------------------------------------------
// gr_pack: blocks 0-1 psi A-frag image (R7-verified); blocks 2-33 feats
// B-frag image with the R15 K-slot permutation gamma(q,e) = e<4 ? 4q+e
// : 16+4q+(e-4) (verified: absmax unchanged in R15's run).
// ---------------------------------------------------------------------------
__global__ __launch_bounds__(256) void gr_pack(
    const float* __restrict__ means,
    const float* __restrict__ scales,
    const float* __restrict__ rots,
    const float* __restrict__ opac,
    const float* __restrict__ cam,
    const float* __restrict__ feats,
    unsigned* __restrict__ psi,
    unsigned* __restrict__ ftg)
{
    const int b = blockIdx.x;
    const int tid = threadIdx.x;

    if (b < 2) {
        const int n = b * 256 + tid;   // 0..511

        float mx = means[n * 3 + 0];
        float my = means[n * 3 + 1];
        float mz = means[n * 3 + 2];

        float h0 = cam[0]  * mx + cam[1]  * my + cam[2]  * mz + cam[3];
        float h1 = cam[4]  * mx + cam[5]  * my + cam[6]  * mz + cam[7];
        float h2 = cam[8]  * mx + cam[9]  * my + cam[10] * mz + cam[11];
        float h3 = cam[12] * mx + cam[13] * my + cam[14] * mz + cam[15];
        float ih3 = 1.0f / h3;
        mx = h0 * ih3; my = h1 * ih3; mz = h2 * ih3;

        float qw = rots[n * 4 + 0];
        float qx = rots[n * 4 + 1];
        float qy = rots[n * 4 + 2];
        float qz = rots[n * 4 + 3];
        float qinv = 1.0f / sqrtf(qw * qw + qx * qx + qy * qy + qz * qz);
        qw *= qinv; qx *= qinv; qy *= qinv; qz *= qinv;

        float R00 = 1.0f - 2.0f * (qy * qy + qz * qz);
        float R01 = 2.0f * (qx * qy - qw * qz);
        float R02 = 2.0f * (qx * qz + qw * qy);
        float R10 = 2.0f * (qx * qy + qw * qz);
        float R11 = 1.0f - 2.0f * (qx * qx + qz * qz);
        float R12 = 2.0f * (qy * qz - qw * qx);
        float R20 = 2.0f * (qx * qz - qw * qy);
        float R21 = 2.0f * (qy * qz + qw * qx);
        float R22 = 1.0f - 2.0f * (qx * qx + qy * qy);

        float s0 = scales[n * 3 + 0];
        float s1 = scales[n * 3 + 1];
        float s2 = scales[n * 3 + 2];
        const float es = 0.7213475204444817f;   // 0.5*log2(e)
        float i0 = es / (s0 * s0);
        float i1 = es / (s1 * s1);
        float i2 = es / (s2 * s2);

        float a00 = R00 * R00 * i0 + R01 * R01 * i1 + R02 * R02 * i2;
        float a01 = R00 * R10 * i0 + R01 * R11 * i1 + R02 * R12 * i2;
        float a02 = R00 * R20 * i0 + R01 * R21 * i1 + R02 * R22 * i2;
        float a11 = R10 * R10 * i0 + R11 * R11 * i1 + R12 * R12 * i2;
        float a12 = R10 * R20 * i0 + R11 * R21 * i1 + R12 * R22 * i2;
        float a22 = R20 * R20 * i0 + R21 * R21 * i1 + R22 * R22 * i2;

        float amx = a00 * mx + a01 * my + a02 * mz;
        float amy = a01 * mx + a11 * my + a12 * mz;
        float amz = a02 * mx + a12 * my + a22 * mz;

        float psv[10];
        psv[0] = -a00; psv[1] = -a11; psv[2] = -a22;
        psv[3] = -2.0f * a01; psv[4] = -2.0f * a02; psv[5] = -2.0f * a12;
        psv[6] = 2.0f * amx; psv[7] = 2.0f * amy; psv[8] = 2.0f * amz;
        psv[9] = __log2f(opac[n]) - (mx * amx + my * amy + mz * amz);

        __fp16 s[32];
#pragma unroll
        for (int i = 0; i < 10; ++i) {
            __fp16 hi = (__fp16)psv[i];
            __fp16 lo = (__fp16)(psv[i] - (float)hi);
            s[i] = hi; s[10 + i] = lo; s[20 + i] = hi;
        }
        s[30] = (__fp16)0.f; s[31] = (__fp16)0.f;

        unsigned* base = psi + (n >> 4) * 256;
        const int lr = n & 15;
#pragma unroll
        for (int q = 0; q < 4; ++q)
#pragma unroll
            for (int jp = 0; jp < 4; ++jp)
                base[(lr + 16 * q) * 4 + jp] = packh(s[8 * q + 2 * jp], s[8 * q + 2 * jp + 1]);
    } else {
        int d = (b - 2) * 256 + tid;   // 0..8191
        int c  = d >> 9;
        int r  = d & 511;
        int nt = r >> 8;
        int l  = (r >> 2) & 63;
        int jp = r & 3;
        int n  = nt * 16 + (l & 15);
        int q  = l >> 4;
        // R15 K-permutation: k-slot (q, e=2jp) -> gaussian gamma(q,e).
        int k0 = c * 32 + ((jp < 2) ? (4 * q + 2 * jp) : (12 + 4 * q + 2 * jp));
        ftg[d] = pkrtz(feats[k0 * NF + n], feats[(k0 + 1) * NF + n]);
    }
}

// ---------------------------------------------------------------------------
// gr_chunk R16: fully in-register, ZERO DS ops. Per nt: Q-MFMA (m0,m1) ->
// f32 alphas -> local exclusive prefixes + group product P -> cross-quad
// exclusive scan via permlane_swap (VALU; see quad_scan) -> weights packed
// straight into the PV A-fragment (ftg K-permuted to match) -> PV MFMA.
// Chain order = original gaussian order, verified in R15 (absmax identical).
// ---------------------------------------------------------------------------
__device__ __forceinline__ void gr_chunk(
    const unsigned* __restrict__ psi,
    const unsigned* __restrict__ ftg,
    int c, int quad, int lane,
    const FRAG (&phif)[4], f32x4 (&pvacc)[4][2], float (&T)[4])
{
    FRAG pa0, pa1, bf0, bf1;
    pa0.v = ((const uint4v*)(psi + (2 * c + 0) * 256))[lane];
    pa1.v = ((const uint4v*)(psi + (2 * c + 1) * 256))[lane];
    bf0.v = ((const uint4v*)(ftg + c * 512 + 0))[lane];
    bf1.v = ((const uint4v*)(ftg + c * 512 + 256))[lane];

#pragma unroll
    for (int nt = 0; nt < 4; ++nt) {
        f32x4 qa0 = __builtin_amdgcn_mfma_f32_16x16x32_f16(
            pa0.h, phif[nt].h, (f32x4){0.f, 0.f, 0.f, 0.f}, 0, 0, 0);
        f32x4 qa1 = __builtin_amdgcn_mfma_f32_16x16x32_f16(
            pa1.h, phif[nt].h, (f32x4){0.f, 0.f, 0.f, 0.f}, 0, 0, 0);

        float a00 = __builtin_amdgcn_exp2f(qa0[0]);
        float a01 = __builtin_amdgcn_exp2f(qa0[1]);
        float a02 = __builtin_amdgcn_exp2f(qa0[2]);
        float a03 = __builtin_amdgcn_exp2f(qa0[3]);
        float a10 = __builtin_amdgcn_exp2f(qa1[0]);
        float a11 = __builtin_amdgcn_exp2f(qa1[1]);
        float a12 = __builtin_amdgcn_exp2f(qa1[2]);
        float a13 = __builtin_amdgcn_exp2f(qa1[3]);

        // local exclusive prefixes (within the lane's 4 gaussians) + group P
        float pr01 = 1.0f - a00;
        float pr02 = pr01 * (1.0f - a01);
        float pr03 = pr02 * (1.0f - a02);
        float P0   = pr03 * (1.0f - a03);
        float pr11 = 1.0f - a10;
        float pr12 = pr11 * (1.0f - a11);
        float pr13 = pr12 * (1.0f - a12);
        float P1   = pr13 * (1.0f - a13);

        // cross-quad exclusive scan — VALU permlane path (R16)
        float x0, t0, Pall0, x1, t1, Pall1;
        quad_scan(P0, quad, x0, t0, Pall0);
        quad_scan(P1, quad, x1, t1, Pall1);

        float E0 = ((quad & 1) ? x0 : 1.0f) * ((quad & 2) ? t0 : 1.0f);
        float E1 = ((quad & 1) ? x1 : 1.0f) * ((quad & 2) ? t1 : 1.0f);

        float F0 = T[nt] * E0;
        float F1 = T[nt] * Pall0 * E1;
        T[nt] *= Pall0 * Pall1;

        FRAG af;
        af.u[0] = pkrtz(F0 * a00,        F0 * pr01 * a01);
        af.u[1] = pkrtz(F0 * pr02 * a02, F0 * pr03 * a03);
        af.u[2] = pkrtz(F1 * a10,        F1 * pr11 * a11);
        af.u[3] = pkrtz(F1 * pr12 * a12, F1 * pr13 * a13);

        pvacc[nt][0] = __builtin_amdgcn_mfma_f32_16x16x32_f16(af.h, bf0.h, pvacc[nt][0], 0, 0, 0);
        pvacc[nt][1] = __builtin_amdgcn_mfma_f32_16x16x32_f16(af.h, bf1.h, pvacc[nt][1], 0, 0, 0);
    }
}

// ---------------------------------------------------------------------------
// gr_render R16: 64 points/block, 8 waves = 8 segments of 64 gaussians.
// Chunks DS-free (permlane scan). LDS only for phi prologue + compose.
// ---------------------------------------------------------------------------
__global__ __launch_bounds__(512, 6) void gr_render(
    const unsigned* __restrict__ psi,
    const unsigned* __restrict__ ftg,
    const float* __restrict__ coords,
    float* __restrict__ out)
{
    __shared__ uint4v sh4[TPB * 5];          // 40960 B: [512 rows][20 dw]
    unsigned* sh = (unsigned*)sh4;

    const int tid  = threadIdx.x;
    const int ln   = tid & 15;
    const int quad = (tid >> 4) & 3;
    const int wv   = tid >> 6;               // 0..7: gaussian segment
    const int lane = tid & 63;

    const int p = blockIdx.x * PTS + lane;   // this lane's point
    const float cx = coords[p * 3 + 0];
    const float cy = coords[p * 3 + 1];
    const float cz = coords[p * 3 + 2];

    // ---- phi' (hi/lo split) -> own wave's LDS rows -> B-frags (R7-verified)
    {
        float ph[10] = {cx * cx, cy * cy, cz * cz, cx * cy, cx * cz, cy * cz,
                        cx, cy, cz, 1.0f};
        __fp16 s[32];
#pragma unroll
        for (int i = 0; i < 10; ++i) {
            __fp16 hi = (__fp16)ph[i];
            __fp16 lo = (__fp16)(ph[i] - (float)hi);
            s[i] = hi; s[10 + i] = hi; s[20 + i] = lo;
        }
        s[30] = (__fp16)0.f; s[31] = (__fp16)0.f;
#pragma unroll
        for (int i = 0; i < 4; ++i) {
            uint4v v = (uint4v){packh(s[8 * i + 0], s[8 * i + 1]),
                                packh(s[8 * i + 2], s[8 * i + 3]),
                                packh(s[8 * i + 4], s[8 * i + 5]),
                                packh(s[8 * i + 6], s[8 * i + 7])};
            *(uint4v*)&sh[ridx(tid, i)] = v;
        }
    }

    FRAG phif[4];
#pragma unroll
    for (int nt = 0; nt < 4; ++nt)
        phif[nt].v = *(const uint4v*)&sh[ridx(wv * 64 + nt * 16 + ln, quad)];

    f32x4 pvacc[4][2];
#pragma unroll
    for (int mt = 0; mt < 4; ++mt) {
        pvacc[mt][0] = (f32x4){0.f, 0.f, 0.f, 0.f};
        pvacc[mt][1] = (f32x4){0.f, 0.f, 0.f, 0.f};
    }
    float T[4] = {1.0f, 1.0f, 1.0f, 1.0f};

    // ---- 2 chunks per segment, all in-register
    const int c0 = wv * CPS;
    gr_chunk(psi, ftg, c0 + 0, quad, lane, phif, pvacc, T);
    gr_chunk(psi, ftg, c0 + 1, quad, lane, phif, pvacc, T);

    // ---- write segment partials (f16 feature-pairs) into own rows; dword d
    // of row p holds features (d, d+16). tT -> spare dword 16 of row
    // (quad*16+ln): all lanes active, ONE ds_write (was 4 exec-masked).
    // T[quad] selected with constant indices (rule #20: no runtime array idx).
    {
        float Tq = (quad == 0) ? T[0] : (quad == 1) ? T[1]
                 : (quad == 2) ? T[2] : T[3];
        sh[(wv * 64 + quad * 16 + ln) * RSTR + 16] = __float_as_uint(Tq);
    }
#pragma unroll
    for (int mt = 0; mt < 4; ++mt)
#pragma unroll
        for (int r = 0; r < 4; ++r)
            sh[(wv * 64 + mt * 16 + quad * 4 + r) * RSTR + ln] =
                pkrtz(pvacc[mt][0][r], pvacc[mt][1][r]);

    __syncthreads();

    // ---- compose segments: out = sum_s (prod_{s'<s} T_s') * acc_s
    if (tid < 256) {
        const int pp = tid >> 2;        // point 0..63
        const int g  = tid & 3;         // dword group (4 dwords)

        float o[8];
#pragma unroll
        for (int j = 0; j < 8; ++j) o[j] = 0.f;
        float w = 1.0f;
#pragma unroll
        for (int s = 0; s < NSEG; ++s) {
            uint4v v = *(const uint4v*)&sh[(s * 64 + pp) * RSTR + g * 4];
            float ts = __uint_as_float(sh[(s * 64 + pp) * RSTR + 16]);
#pragma unroll
            for (int j = 0; j < 4; ++j) {
                H2U u; u.u = v[j];
                o[j]     = fmaf(w, (float)u.h[0], o[j]);
                o[4 + j] = fmaf(w, (float)u.h[1], o[4 + j]);
            }
            w *= ts;
        }

        float* __restrict__ ob = out + (blockIdx.x * PTS + pp) * NF + g * 4;
        *(float4*)ob        = make_float4(o[0], o[1], o[2], o[3]);
        *(float4*)(ob + 16) = make_float4(o[4], o[5], o[6], o[7]);
    }
}

extern "C" void kernel_launch(void* const* d_in, const int* in_sizes, int n_in,
                              void* d_out, int out_size, void* d_ws, size_t ws_size,
                              hipStream_t stream)
{
    const float* means  = (const float*)d_in[0];   // (512,3)
    const float* scales = (const float*)d_in[1];   // (512,3)
    const float* rots   = (const float*)d_in[2];   // (512,4)
    const float* opac   = (const float*)d_in[3];   // (512,1)
    const float* feats  = (const float*)d_in[4];   // (512,32)
    const float* cam    = (const float*)d_in[5];   // (4,4)
    const float* coords = (const float*)d_in[6];   // (96,96,16,3)
    float* out = (float*)d_out;                    // (96,96,16,32) fp32

    unsigned* psi = (unsigned*)d_ws;               // 32 KiB: gaussian A-frag image
    unsigned* ftg = psi + 32 * 256;                // 32 KiB: feats B-frag image

    gr_pack<<<34, 256, 0, stream>>>(means, scales, rots, opac, cam, feats, psi, ftg);
    gr_render<<<NP / PTS, TPB, 0, stream>>>(psi, ftg, coords, out);
}

// Round 10
// 92.680 us; speedup vs baseline: 1.3528x; 1.3528x over previous
//
#include <hip/hip_runtime.h>

#define NG 512
#define NF 32
#define NP (96 * 96 * 16)   // 147456 points
#define TPB 512             // 8 waves; 64 points per block, 8 gaussian segments
#define PTS 64
#define NSEG 8
#define CPS 2               // chunks (of 32 gaussians) per segment
#define RSTR 20             // LDS row stride in dwords (80 B), bank-spread (R12)

typedef _Float16 half8 __attribute__((ext_vector_type(8)));
typedef __fp16  fp16x2 __attribute__((ext_vector_type(2)));
typedef float f32x4 __attribute__((ext_vector_type(4)));
typedef unsigned uint4v __attribute__((ext_vector_type(4)));
typedef unsigned uint2v __attribute__((ext_vector_type(2)));

union H2U { fp16x2 h; unsigned u; };
union FRAG { unsigned u[4]; uint4v v; half8 h; };

__device__ __forceinline__ unsigned packh(__fp16 a, __fp16 b) {
    H2U p; p.h = (fp16x2){a, b}; return p.u;
}
__device__ __forceinline__ unsigned pkrtz(float a, float b) {
    H2U p; p.h = __builtin_amdgcn_cvt_pkrtz(a, b); return p.u;
}
// R12: dword index into a [512 rows][20 dw] LDS image, linear in-row slots.
// Dwords 0..15 hold frag data; dword 16 holds the segment transmittance.
__device__ __forceinline__ int ridx(int row, int grp) {
    return row * RSTR + 4 * grp;
}

// ---------------------------------------------------------------------------
// gr_pack (R7+-verified, R14 layout — NO K-permutation): blocks 0-1 psi
// A-frag image; blocks 2-33 feats B-frag image.
// ---------------------------------------------------------------------------
__global__ __launch_bounds__(256) void gr_pack(
    const float* __restrict__ means,
    const float* __restrict__ scales,
    const float* __restrict__ rots,
    const float* __restrict__ opac,
    const float* __restrict__ cam,
    const float* __restrict__ feats,
    unsigned* __restrict__ psi,
    unsigned* __restrict__ ftg)
{
    const int b = blockIdx.x;
    const int tid = threadIdx.x;

    if (b < 2) {
        const int n = b * 256 + tid;   // 0..511

        float mx = means[n * 3 + 0];
        float my = means[n * 3 + 1];
        float mz = means[n * 3 + 2];

        float h0 = cam[0]  * mx + cam[1]  * my + cam[2]  * mz + cam[3];
        float h1 = cam[4]  * mx + cam[5]  * my + cam[6]  * mz + cam[7];
        float h2 = cam[8]  * mx + cam[9]  * my + cam[10] * mz + cam[11];
        float h3 = cam[12] * mx + cam[13] * my + cam[14] * mz + cam[15];
        float ih3 = 1.0f / h3;
        mx = h0 * ih3; my = h1 * ih3; mz = h2 * ih3;

        float qw = rots[n * 4 + 0];
        float qx = rots[n * 4 + 1];
        float qy = rots[n * 4 + 2];
        float qz = rots[n * 4 + 3];
        float qinv = 1.0f / sqrtf(qw * qw + qx * qx + qy * qy + qz * qz);
        qw *= qinv; qx *= qinv; qy *= qinv; qz *= qinv;

        float R00 = 1.0f - 2.0f * (qy * qy + qz * qz);
        float R01 = 2.0f * (qx * qy - qw * qz);
        float R02 = 2.0f * (qx * qz + qw * qy);
        float R10 = 2.0f * (qx * qy + qw * qz);
        float R11 = 1.0f - 2.0f * (qx * qx + qz * qz);
        float R12 = 2.0f * (qy * qz - qw * qx);
        float R20 = 2.0f * (qx * qz - qw * qy);
        float R21 = 2.0f * (qy * qz + qw * qx);
        float R22 = 1.0f - 2.0f * (qx * qx + qy * qy);

        float s0 = scales[n * 3 + 0];
        float s1 = scales[n * 3 + 1];
        float s2 = scales[n * 3 + 2];
        const float es = 0.7213475204444817f;   // 0.5*log2(e)
        float i0 = es / (s0 * s0);
        float i1 = es / (s1 * s1);
        float i2 = es / (s2 * s2);

        float a00 = R00 * R00 * i0 + R01 * R01 * i1 + R02 * R02 * i2;
        float a01 = R00 * R10 * i0 + R01 * R11 * i1 + R02 * R12 * i2;
        float a02 = R00 * R20 * i0 + R01 * R21 * i1 + R02 * R22 * i2;
        float a11 = R10 * R10 * i0 + R11 * R11 * i1 + R12 * R12 * i2;
        float a12 = R10 * R20 * i0 + R11 * R21 * i1 + R12 * R22 * i2;
        float a22 = R20 * R20 * i0 + R21 * R21 * i1 + R22 * R22 * i2;

        float amx = a00 * mx + a01 * my + a02 * mz;
        float amy = a01 * mx + a11 * my + a12 * mz;
        float amz = a02 * mx + a12 * my + a22 * mz;

        float psv[10];
        psv[0] = -a00; psv[1] = -a11; psv[2] = -a22;
        psv[3] = -2.0f * a01; psv[4] = -2.0f * a02; psv[5] = -2.0f * a12;
        psv[6] = 2.0f * amx; psv[7] = 2.0f * amy; psv[8] = 2.0f * amz;
        psv[9] = __log2f(opac[n]) - (mx * amx + my * amy + mz * amz);

        __fp16 s[32];
#pragma unroll
        for (int i = 0; i < 10; ++i) {
            __fp16 hi = (__fp16)psv[i];
            __fp16 lo = (__fp16)(psv[i] - (float)hi);
            s[i] = hi; s[10 + i] = lo; s[20 + i] = hi;
        }
        s[30] = (__fp16)0.f; s[31] = (__fp16)0.f;

        unsigned* base = psi + (n >> 4) * 256;
        const int lr = n & 15;
#pragma unroll
        for (int q = 0; q < 4; ++q)
#pragma unroll
            for (int jp = 0; jp < 4; ++jp)
                base[(lr + 16 * q) * 4 + jp] = packh(s[8 * q + 2 * jp], s[8 * q + 2 * jp + 1]);
    } else {
        int d = (b - 2) * 256 + tid;   // 0..8191
        int c  = d >> 9;
        int r  = d & 511;
        int nt = r >> 8;
        int l  = (r >> 2) & 63;
        int jp = r & 3;
        int n  = nt * 16 + (l & 15);
        int k0 = c * 32 + (l >> 4) * 8 + 2 * jp;
        ftg[d] = pkrtz(feats[k0 * NF + n], feats[(k0 + 1) * NF + n]);
    }
}

// ---------------------------------------------------------------------------
// Chunk body (R10/R12-verified math, bit-identical; R14 structure).
// ---------------------------------------------------------------------------
__device__ __forceinline__ void gr_chunk(
    const unsigned* __restrict__ psi,
    const unsigned* __restrict__ ftg,
    unsigned* sh,
    int c,
    int tid, int ln, int quad, int wv, int lane,
    const FRAG (&phif)[4], f32x4 (&pvacc)[4][2], float& T)
{
    // ---- VMEM: this chunk's A- and B-frags, one issue burst
    FRAG pa0, pa1, bf0, bf1;
    pa0.v = ((const uint4v*)(psi + (2 * c + 0) * 256))[lane];
    pa1.v = ((const uint4v*)(psi + (2 * c + 1) * 256))[lane];
    bf0.v = ((const uint4v*)(ftg + c * 512 + 0))[lane];
    bf1.v = ((const uint4v*)(ftg + c * 512 + 256))[lane];

    // ---- Q GEMM + exp2, per nt (minimal qa liveness)
#pragma unroll
    for (int m = 0; m < 2; ++m) {
        const FRAG& pa = m ? pa1 : pa0;
#pragma unroll
        for (int nt = 0; nt < 4; ++nt) {
            f32x4 qa = __builtin_amdgcn_mfma_f32_16x16x32_f16(
                pa.h, phif[nt].h, (f32x4){0.f, 0.f, 0.f, 0.f}, 0, 0, 0);
            float a0 = __builtin_amdgcn_exp2f(qa[0]);
            float a1 = __builtin_amdgcn_exp2f(qa[1]);
            float a2 = __builtin_amdgcn_exp2f(qa[2]);
            float a3 = __builtin_amdgcn_exp2f(qa[3]);
            const int row = wv * 64 + nt * 16 + ln;
            const int dbase = row * RSTR + (m * 8 + quad * 2);
            *(uint2v*)&sh[dbase] = (uint2v){pkrtz(a0, a1), pkrtz(a2, a3)};
        }
    }

    // ---- T-chain, quad-factored (R10-verified): cumulative (1-a) products
    // off the T critical path; only T *= p is serial (1 mul per 4 gaussians).
#pragma unroll
    for (int i = 0; i < 4; ++i) {
        uint4v a4 = *(const uint4v*)&sh[ridx(tid, i)];
        uint4v w4;
#pragma unroll
        for (int h = 0; h < 2; ++h) {
            H2U u0; u0.u = a4[2 * h + 0];
            H2U u1; u1.u = a4[2 * h + 1];
            float a0 = (float)u0.h[0];
            float a1 = (float)u0.h[1];
            float a2 = (float)u1.h[0];
            float a3 = (float)u1.h[1];
            float c1 = 1.0f - a0;
            float t1 = c1 * a1; float c2 = c1 - t1;
            float t2 = c2 * a2; float c3 = c2 - t2;
            float t3 = c3 * a3; float pq = c3 - t3;
            float w0 = T * a0;
            float w1 = T * t1;
            float w2 = T * t2;
            float w3 = T * t3;
            T = T * pq;
            w4[2 * h + 0] = pkrtz(w0, w1);
            w4[2 * h + 1] = pkrtz(w2, w3);
        }
        *(uint4v*)&sh[ridx(tid, i)] = w4;
    }

    // ---- PV GEMM (R6+-verified path)
#pragma unroll
    for (int mt = 0; mt < 4; ++mt) {
        FRAG af;
        af.v = *(const uint4v*)&sh[ridx(wv * 64 + mt * 16 + ln, quad)];
        pvacc[mt][0] = __builtin_amdgcn_mfma_f32_16x16x32_f16(af.h, bf0.h, pvacc[mt][0], 0, 0, 0);
        pvacc[mt][1] = __builtin_amdgcn_mfma_f32_16x16x32_f16(af.h, bf1.h, pvacc[mt][1], 0, 0, 0);
    }
}

// ---------------------------------------------------------------------------
// gr_render R17 = R14 (best verified, 94.0 µs) + NONTEMPORAL output stores.
// R16's profile showed the kernel is HBM-traffic-bound (render dur ==
// traffic/BW) with WRITE ~5x the 18.9 MB output and FETCH ~10x the true
// input set. Theory: the output store stream write-allocates in L2, write-
// back amplifies (2 stores per 128B line at +0/+64) and evicts the hot
// psi/ftg/coords lines. nt stores stream past L2: output no longer
// thrashes the cache. Single-variable change vs R14.
// ---------------------------------------------------------------------------
__global__ __launch_bounds__(512, 6) void gr_render(
    const unsigned* __restrict__ psi,
    const unsigned* __restrict__ ftg,
    const float* __restrict__ coords,
    float* __restrict__ out)
{
    __shared__ uint4v sh4[TPB * 5];          // 40960 B: [512 rows][20 dw]
    unsigned* sh = (unsigned*)sh4;

    const int tid  = threadIdx.x;
    const int ln   = tid & 15;
    const int quad = (tid >> 4) & 3;
    const int wv   = tid >> 6;               // 0..7: gaussian segment
    const int lane = tid & 63;

    const int p = blockIdx.x * PTS + lane;   // this lane's point
    const float cx = coords[p * 3 + 0];
    const float cy = coords[p * 3 + 1];
    const float cz = coords[p * 3 + 2];

    // ---- phi' (hi/lo split) -> own wave's LDS rows -> B-frags (R7-verified)
    {
        float ph[10] = {cx * cx, cy * cy, cz * cz, cx * cy, cx * cz, cy * cz,
                        cx, cy, cz, 1.0f};
        __fp16 s[32];
#pragma unroll
        for (int i = 0; i < 10; ++i) {
            __fp16 hi = (__fp16)ph[i];
            __fp16 lo = (__fp16)(ph[i] - (float)hi);
            s[i] = hi; s[10 + i] = hi; s[20 + i] = lo;
        }
        s[30] = (__fp16)0.f; s[31] = (__fp16)0.f;
#pragma unroll
        for (int i = 0; i < 4; ++i) {
            uint4v v = (uint4v){packh(s[8 * i + 0], s[8 * i + 1]),
                                packh(s[8 * i + 2], s[8 * i + 3]),
                                packh(s[8 * i + 4], s[8 * i + 5]),
                                packh(s[8 * i + 6], s[8 * i + 7])};
            *(uint4v*)&sh[ridx(tid, i)] = v;
        }
    }

    FRAG phif[4];
#pragma unroll
    for (int nt = 0; nt < 4; ++nt)
        phif[nt].v = *(const uint4v*)&sh[ridx(wv * 64 + nt * 16 + ln, quad)];

    f32x4 pvacc[4][2];
#pragma unroll
    for (int mt = 0; mt < 4; ++mt) {
        pvacc[mt][0] = (f32x4){0.f, 0.f, 0.f, 0.f};
        pvacc[mt][1] = (f32x4){0.f, 0.f, 0.f, 0.f};
    }
    float T = 1.0f;

    // ---- 2 chunks per segment
    const int c0 = wv * CPS;
    gr_chunk(psi, ftg, sh, c0 + 0, tid, ln, quad, wv, lane, phif, pvacc, T);
    gr_chunk(psi, ftg, sh, c0 + 1, tid, ln, quad, wv, lane, phif, pvacc, T);

    // ---- write segment partials (f16 feature-pairs) into own rows; dword d
    // of row p holds features (d, d+16). tT -> spare dword 16 of own row.
    sh[(wv * 64 + lane) * RSTR + 16] = __float_as_uint(T);
#pragma unroll
    for (int mt = 0; mt < 4; ++mt)
#pragma unroll
        for (int r = 0; r < 4; ++r)
            sh[(wv * 64 + mt * 16 + quad * 4 + r) * RSTR + ln] =
                pkrtz(pvacc[mt][0][r], pvacc[mt][1][r]);

    __syncthreads();

    // ---- compose segments: out = sum_s (prod_{s'<s} T_s') * acc_s
    if (tid < 256) {
        const int pp = tid >> 2;        // point 0..63
        const int g  = tid & 3;         // dword group (4 dwords)

        float o[8];
#pragma unroll
        for (int j = 0; j < 8; ++j) o[j] = 0.f;
        float w = 1.0f;
#pragma unroll
        for (int s = 0; s < NSEG; ++s) {
            uint4v v = *(const uint4v*)&sh[(s * 64 + pp) * RSTR + g * 4];
            float ts = __uint_as_float(sh[(s * 64 + pp) * RSTR + 16]);
#pragma unroll
            for (int j = 0; j < 4; ++j) {
                H2U u; u.u = v[j];
                o[j]     = fmaf(w, (float)u.h[0], o[j]);
                o[4 + j] = fmaf(w, (float)u.h[1], o[4 + j]);
            }
            w *= ts;
        }

        // R17: nontemporal (nt) streaming stores — bypass L2 write-allocate.
        float* __restrict__ ob = out + (blockIdx.x * PTS + pp) * NF + g * 4;
        __builtin_nontemporal_store((f32x4){o[0], o[1], o[2], o[3]},
                                    (f32x4*)ob);
        __builtin_nontemporal_store((f32x4){o[4], o[5], o[6], o[7]},
                                    (f32x4*)(ob + 16));
    }
}

extern "C" void kernel_launch(void* const* d_in, const int* in_sizes, int n_in,
                              void* d_out, int out_size, void* d_ws, size_t ws_size,
                              hipStream_t stream)
{
    const float* means  = (const float*)d_in[0];   // (512,3)
    const float* scales = (const float*)d_in[1];   // (512,3)
    const float* rots   = (const float*)d_in[2];   // (512,4)
    const float* opac   = (const float*)d_in[3];   // (512,1)
    const float* feats  = (const float*)d_in[4];   // (512,32)
    const float* cam    = (const float*)d_in[5];   // (4,4)
    const float* coords = (const float*)d_in[6];   // (96,96,16,3)
    float* out = (float*)d_out;                    // (96,96,16,32) fp32

    unsigned* psi = (unsigned*)d_ws;               // 32 KiB: gaussian A-frag image
    unsigned* ftg = psi + 32 * 256;                // 32 KiB: feats B-frag image

    gr_pack<<<34, 256, 0, stream>>>(means, scales, rots, opac, cam, feats, psi, ftg);
    gr_render<<<NP / PTS, TPB, 0, stream>>>(psi, ftg, coords, out);
}